// Round 9
// baseline (459.213 us; speedup 1.0000x reference)
//
#include <hip/hip_runtime.h>
#include <cstddef>
#include <cstdint>

// Problem: B=2, S=2048, E=1024, H=16, D=64.  Softmax over HEADS (ref quirk).
#define BATCH 2
#define S_LEN 2048
#define E_DIM 1024
#define NH    16
#define HD    64
#define M_ROWS (BATCH * S_LEN)   // 4096
#define KSPLIT 4
#define KSEG   (S_LEN / KSPLIT)  // 512

// fold softmax scale into Q at projection time: 1/sqrt(64) * log2(e)
#define QSCALE 0.18033688011112042f

typedef unsigned short u16;
typedef short     bf16x8 __attribute__((ext_vector_type(8)));
typedef _Float16  f16x8  __attribute__((ext_vector_type(8)));
typedef __fp16    h16x2  __attribute__((ext_vector_type(2)));   // cvt_pkrtz return type
typedef float     f32x4  __attribute__((ext_vector_type(4)));

__device__ __forceinline__ u16 f2bf(float f) {
    union { float f; unsigned u; } v; v.f = f;
    unsigned r = v.u + 0x7fffu + ((v.u >> 16) & 1u);   // RNE
    return (u16)(r >> 16);
}
__device__ __forceinline__ float bf2f(u16 h) {
    union { unsigned u; float f; } v; v.u = ((unsigned)h) << 16;
    return v.f;
}

// async global->LDS DMA, 16 B per lane (global_load_lds_dwordx4).
__device__ __forceinline__ void load_lds16(const u16* g, u16* l) {
    __builtin_amdgcn_global_load_lds(
        (const __attribute__((address_space(1))) unsigned int*)g,
        (__attribute__((address_space(3))) unsigned int*)l, 16, 0, 0);
}

// ---------------------------------------------------------------------------
// fp32 -> bf16 bulk convert (n % 4 == 0)
// ---------------------------------------------------------------------------
__global__ void cvt_bf16(const float* __restrict__ in, u16* __restrict__ out, int n)
{
    int i = (blockIdx.x * 256 + threadIdx.x) * 4;
    if (i + 3 < n) {
        float4 v = *(const float4*)(in + i);
        u16 o[4] = { f2bf(v.x), f2bf(v.y), f2bf(v.z), f2bf(v.w) };
        *(uint2*)(out + i) = *(const uint2*)o;
    }
}

// three QKV weight matrices -> concat bf16 buffer, one launch (grid.y = seg)
__global__ void cvt_w3(const float* __restrict__ Wq, const float* __restrict__ Wk,
                       const float* __restrict__ Wv, u16* __restrict__ out)
{
    const int seg = blockIdx.y;
    const float* src = (seg == 0) ? Wq : (seg == 1) ? Wk : Wv;
    int i = (blockIdx.x * 256 + threadIdx.x) * 4;
    float4 v = *(const float4*)(src + i);
    u16 o[4] = { f2bf(v.x), f2bf(v.y), f2bf(v.z), f2bf(v.w) };
    *(uint2*)(out + (size_t)seg * E_DIM * E_DIM + i) = *(const uint2*)o;
}

// ---------------------------------------------------------------------------
// ctx = a + b + c + d  (bf16 in, fp32 add, bf16 out).  In-place on a is safe.
// ---------------------------------------------------------------------------
__global__ void combine_ctx4(const u16* __restrict__ a, const u16* __restrict__ b,
                             const u16* __restrict__ c, const u16* __restrict__ d,
                             u16* __restrict__ o, int n)
{
    int i = (blockIdx.x * 256 + threadIdx.x) * 4;
    if (i + 3 < n) {
        uint2 ua = *(const uint2*)(a + i);
        uint2 ub = *(const uint2*)(b + i);
        uint2 uc = *(const uint2*)(c + i);
        uint2 ud = *(const uint2*)(d + i);
        const u16* pa = (const u16*)&ua; const u16* pb = (const u16*)&ub;
        const u16* pc = (const u16*)&uc; const u16* pd = (const u16*)&ud;
        u16 ov[4];
#pragma unroll
        for (int j = 0; j < 4; ++j)
            ov[j] = f2bf(bf2f(pa[j]) + bf2f(pb[j]) + bf2f(pc[j]) + bf2f(pd[j]));
        *(uint2*)(o + i) = *(const uint2*)ov;
    }
}

// ---------------------------------------------------------------------------
// Fused QKV projection GEMM (m97-style DMA staging).
//   seg 0 -> Q, bf16, PRE-SCALED by QSCALE (softmax scale folded in)
//   seg 1 -> K, bf16
//   seg 2 -> V, written TRANSPOSED Vt[b][e][s] in FP16 (PV runs fp16 MFMA)
// ---------------------------------------------------------------------------
__global__ __launch_bounds__(256)
void gemm_qkv(const u16* __restrict__ A, const u16* __restrict__ W3,
              const float* __restrict__ bq, const float* __restrict__ bk,
              const float* __restrict__ bv,
              u16* __restrict__ Qb, u16* __restrict__ Kb, u16* __restrict__ Vtb)
{
    __shared__ u16 Al[128 * 32];
    __shared__ u16 Bl[128 * 32];
    const int K = E_DIM;
    const int t = threadIdx.x;
    const int w = t >> 6, lane = t & 63;
    const int quad = lane >> 4, lm = lane & 15;
    const int wy = w >> 1, wx = w & 1;
    const int m0 = blockIdx.x * 128, n0 = blockIdx.y * 128;
    const int lrow  = lane >> 2;
    const int lcol8 = (lane & 3) * 8;

    f32x4 acc[4][4] = {};

    for (int kb = 0; kb < K; kb += 32) {
        __syncthreads();
#pragma unroll
        for (int i = 0; i < 2; ++i) {
            const int r0 = w * 32 + i * 16;
            load_lds16(A  + (size_t)(m0 + r0 + lrow) * K + kb + lcol8, &Al[r0 * 32]);
            load_lds16(W3 + (size_t)(n0 + r0 + lrow) * K + kb + lcol8, &Bl[r0 * 32]);
        }
        __syncthreads();

        bf16x8 af[4], bfr[4];
#pragma unroll
        for (int i = 0; i < 4; ++i)
            af[i] = *(const bf16x8*)(Al + (wy * 64 + i * 16 + lm) * 32 + quad * 8);
#pragma unroll
        for (int j = 0; j < 4; ++j)
            bfr[j] = *(const bf16x8*)(Bl + (wx * 64 + j * 16 + lm) * 32 + quad * 8);
#pragma unroll
        for (int i = 0; i < 4; ++i)
#pragma unroll
            for (int j = 0; j < 4; ++j)
                acc[i][j] = __builtin_amdgcn_mfma_f32_16x16x32_bf16(af[i], bfr[j], acc[i][j], 0, 0, 0);
    }

    const int seg = n0 >> 10;            // 0=Q, 1=K, 2=V
    const int nl0 = n0 & 1023;
    const float* bs = (seg == 0) ? bq : (seg == 1) ? bk : bv;

    if (seg < 2) {
        u16* dst = (seg == 0) ? Qb : Kb;
        const float scl = (seg == 0) ? QSCALE : 1.0f;
#pragma unroll
        for (int j = 0; j < 4; ++j) {
            const int n = nl0 + wx * 64 + j * 16 + lm;
            const float bias = bs[n];
#pragma unroll
            for (int i = 0; i < 4; ++i) {
                const int mrow = m0 + wy * 64 + i * 16 + quad * 4;
#pragma unroll
                for (int rg = 0; rg < 4; ++rg)
                    dst[(size_t)(mrow + rg) * E_DIM + n] = f2bf((acc[i][j][rg] + bias) * scl);
            }
        }
    } else {
        // V: fp16, transposed -> Vt[b][e][s]
#pragma unroll
        for (int j = 0; j < 4; ++j) {
            const int n = nl0 + wx * 64 + j * 16 + lm;
            const float bias = bs[n];
#pragma unroll
            for (int i = 0; i < 4; ++i) {
                const int mrow = m0 + wy * 64 + i * 16 + quad * 4;
                const int batch = mrow >> 11;
                const int sloc  = mrow & 2047;
                u16 o[4];
#pragma unroll
                for (int rg = 0; rg < 4; ++rg) {
                    union { _Float16 h; u16 u; } cv;
                    cv.h = (_Float16)(acc[i][j][rg] + bias);
                    o[rg] = cv.u;
                }
                *(uint2*)&Vtb[(size_t)batch * E_DIM * S_LEN + (size_t)n * S_LEN + sloc]
                    = *(const uint2*)o;
            }
        }
    }
}

// ---------------------------------------------------------------------------
// Output projection GEMM — unchanged.
// ---------------------------------------------------------------------------
__global__ __launch_bounds__(256)
void gemm_wo(const u16* __restrict__ A, const u16* __restrict__ B,
             const float* __restrict__ bias, float* __restrict__ C)
{
    __shared__ u16 Al[128 * 32];
    __shared__ u16 Bl[128 * 32];
    const int K = E_DIM, N = E_DIM;
    const int t = threadIdx.x;
    const int w = t >> 6, lane = t & 63;
    const int quad = lane >> 4, lm = lane & 15;
    const int wy = w >> 1, wx = w & 1;
    const int m0 = blockIdx.x * 128, n0 = blockIdx.y * 128;
    const int lrow  = lane >> 2;
    const int lcol8 = (lane & 3) * 8;

    f32x4 acc[4][4] = {};

    for (int kb = 0; kb < K; kb += 32) {
        __syncthreads();
#pragma unroll
        for (int i = 0; i < 2; ++i) {
            const int r0 = w * 32 + i * 16;
            load_lds16(A + (size_t)(m0 + r0 + lrow) * K + kb + lcol8, &Al[r0 * 32]);
            load_lds16(B + (size_t)(n0 + r0 + lrow) * K + kb + lcol8, &Bl[r0 * 32]);
        }
        __syncthreads();

        bf16x8 af[4], bfr[4];
#pragma unroll
        for (int i = 0; i < 4; ++i)
            af[i] = *(const bf16x8*)(Al + (wy * 64 + i * 16 + lm) * 32 + quad * 8);
#pragma unroll
        for (int j = 0; j < 4; ++j)
            bfr[j] = *(const bf16x8*)(Bl + (wx * 64 + j * 16 + lm) * 32 + quad * 8);
#pragma unroll
        for (int i = 0; i < 4; ++i)
#pragma unroll
            for (int j = 0; j < 4; ++j)
                acc[i][j] = __builtin_amdgcn_mfma_f32_16x16x32_bf16(af[i], bfr[j], acc[i][j], 0, 0, 0);
    }

#pragma unroll
    for (int j = 0; j < 4; ++j) {
        const int n = n0 + wx * 64 + j * 16 + lm;
        const float bs = bias[n];
#pragma unroll
        for (int i = 0; i < 4; ++i) {
            const int mrow = m0 + wy * 64 + i * 16 + quad * 4;
#pragma unroll
            for (int rg = 0; rg < 4; ++rg)
                C[(size_t)(mrow + rg) * N + n] = acc[i][j][rg] + bs;
        }
    }
}

// ---------------------------------------------------------------------------
// attn_v11 = v10 + register diet to fit 3 waves/SIMD in the UNIFIED
// VGPR+AGPR file (R8 lesson: occupancy = 512 / (arch + acc regs); v10's
// ~116 arch + 64 acc = ~180 -> 2 waves/SIMD).
//   diet 1: V prefetch split 64 -> 32 regs: vfA (heads w*4..w*4+1) loaded
//           before B2; vfB (heads w*4+2..3) loaded AFTER PV-A frees vfA.
//   diet 2: in-place per-ks softmax (no pv[2][16] array; 16 live regs),
//           P writes as 2x16 ds_write_b16.
//   Peak ~ qf32 + vfA32 + s16 + acc64 + addr ~ 159 <= 170 = 512/3.
//   __launch_bounds__(256, 3) enforces the cap.  KSPLIT=4 + XCD pinning
//   kept (grid 1024 -> 1.33 residency passes at 3 blocks/CU vs 2.0 at 2).
// ---------------------------------------------------------------------------
__global__ __launch_bounds__(256, 3)
void attn_v11(const u16* __restrict__ Q, const u16* __restrict__ K,
              const u16* __restrict__ Vt,
              u16* __restrict__ c0, u16* __restrict__ c1,
              u16* __restrict__ c2, u16* __restrict__ c3)
{
    __shared__ __align__(16) u16 smem[19456];   // 38912 B
    u16* S4h = smem;                 // [512 slots][18] fp16 halves = 18432 B
    u16* P5  = smem + 9216;          // [16h][16q][40] halves      = 20480 B

    const int t     = threadIdx.x;
    const int w     = t >> 6, lane = t & 63;
    const int quad  = lane >> 4, lm = lane & 15;

    // combo->XCD pinning (model: XCD = blockIdx % 8): 8 combos (b,kq), one
    // per XCD; each combo's K-quarter (1MB) + V-quarter (1MB) is L2-resident.
    const int i     = blockIdx.x;       // 0..1023
    const int combo = i & 7;
    const int b     = combo >> 2;
    const int kq    = combo & 3;
    const int qt    = i >> 3;           // 0..127
    const int q0    = qt * 16;

    const size_t qbase = ((size_t)b * S_LEN + q0) * E_DIM;
    const size_t kmat  = (size_t)b * S_LEN * E_DIM;
    const size_t vtb   = (size_t)b * E_DIM * S_LEN;

    // Q fragments (B-operand of swapped QK^T), loop-invariant
    bf16x8 qf[4][2];
#pragma unroll
    for (int h2 = 0; h2 < 4; ++h2)
#pragma unroll
        for (int hf = 0; hf < 2; ++hf)
            qf[h2][hf] = *(const bf16x8*)(Q + qbase + (size_t)lm * E_DIM
                                          + (w * 4 + h2) * 64 + hf * 32 + quad * 8);

    f32x4 oacc[4][4] = {};   // [h2][dtile]
    const int kbeg = kq * KSEG;
    const int sq = t & 15, sj = t >> 4;   // softmax slot: q=sq, k in {2sj, 2sj+1}

    for (int c = 0; c < KSEG / 32; ++c) {   // 16 chunks
        const int k0 = kbeg + c * 32;

        // ---- swapped QK^T: S[k][q] for this wave's 4 heads ----
        f32x4 sacc[4][2];
#pragma unroll
        for (int h2 = 0; h2 < 4; ++h2) {
            const int h = w * 4 + h2;
#pragma unroll
            for (int kt = 0; kt < 2; ++kt) {
                f32x4 sf = {};
#pragma unroll
                for (int hf = 0; hf < 2; ++hf) {
                    bf16x8 kf = *(const bf16x8*)(K + kmat
                                 + (size_t)(k0 + kt * 16 + lm) * E_DIM
                                 + h * 64 + hf * 32 + quad * 8);
                    sf = __builtin_amdgcn_mfma_f32_16x16x32_bf16(kf, qf[h2][hf], sf, 0, 0, 0);
                }
                sacc[h2][kt] = sf;
            }
        }

        // ---- pack 4 heads per (k,q) slot -> fp16, one b64 store each ----
        // (no barrier needed: all waves' S4h reads retired at prev B3)
#pragma unroll
        for (int kt = 0; kt < 2; ++kt)
#pragma unroll
            for (int rg = 0; rg < 4; ++rg) {
                union { h16x2 v; unsigned u; } p0, p1;
                p0.v = __builtin_amdgcn_cvt_pkrtz(sacc[0][kt][rg], sacc[1][kt][rg]);
                p1.v = __builtin_amdgcn_cvt_pkrtz(sacc[2][kt][rg], sacc[3][kt][rg]);
                uint2 pk; pk.x = p0.u; pk.y = p1.u;
                const int kl = kt * 16 + quad * 4 + rg;
                *(uint2*)(S4h + (size_t)(kl * 16 + lm) * 18 + w * 4) = pk;
            }

        // ---- V prefetch A: heads w*4, w*4+1 (32 regs, not 64) ----
        f16x8 vfA[2][4];
#pragma unroll
        for (int h2 = 0; h2 < 2; ++h2)
#pragma unroll
            for (int dt = 0; dt < 4; ++dt)
                vfA[h2][dt] = *(const f16x8*)(Vt + vtb
                              + (size_t)((w * 4 + h2) * 64 + dt * 16 + lm) * S_LEN
                              + k0 + quad * 8);

        asm volatile("s_waitcnt lgkmcnt(0)" ::: "memory");
        __builtin_amdgcn_s_barrier();   // B2: S4h visible everywhere

        // ---- register softmax over heads, per-ks in place (16 live) ----
#pragma unroll
        for (int ks = 0; ks < 2; ++ks) {
            const u16* base = S4h + (size_t)((2 * sj + ks) * 16 + sq) * 18;
            union { uint4 u; __fp16 h[8]; } r0, r1;
            r0.u = *(const uint4*)(base);
            r1.u = *(const uint4*)(base + 8);
            float s[16];
#pragma unroll
            for (int z = 0; z < 8; ++z) {
                s[z]     = (float)r0.h[z];
                s[8 + z] = (float)r1.h[z];
            }
            float m = s[0];
#pragma unroll
            for (int h = 1; h < 16; ++h) m = fmaxf(m, s[h]);
            float sum = 0.f;
#pragma unroll
            for (int h = 0; h < 16; ++h) {
                s[h] = __builtin_amdgcn_exp2f(s[h] - m);  // scale folded into Q
                sum += s[h];
            }
            const float inv = __builtin_amdgcn_rcpf(sum);
#pragma unroll
            for (int h = 0; h < 16; ++h) {
                union { __fp16 hv; u16 u; } cv;
                cv.hv = (__fp16)(s[h] * inv);
                P5[(size_t)h * 640 + sq * 40 + 2 * sj + ks] = cv.u;
            }
        }

        asm volatile("s_waitcnt lgkmcnt(0)" ::: "memory");
        __builtin_amdgcn_s_barrier();   // B3: P5 visible; all S4h/P5 reads retired

        // ---- PV-A: heads w*4, w*4+1 from vfA ----
#pragma unroll
        for (int h2 = 0; h2 < 2; ++h2) {
            f16x8 pa = *(const f16x8*)(P5 + (size_t)(w * 4 + h2) * 640
                                       + lm * 40 + quad * 8);
#pragma unroll
            for (int dt = 0; dt < 4; ++dt)
                oacc[h2][dt] = __builtin_amdgcn_mfma_f32_16x16x32_f16(pa, vfA[h2][dt],
                                                                      oacc[h2][dt], 0, 0, 0);
        }

        // ---- V prefetch B: heads w*4+2, w*4+3 (reuses vfA's budget) ----
        f16x8 vfB[2][4];
#pragma unroll
        for (int h2 = 0; h2 < 2; ++h2)
#pragma unroll
            for (int dt = 0; dt < 4; ++dt)
                vfB[h2][dt] = *(const f16x8*)(Vt + vtb
                              + (size_t)((w * 4 + 2 + h2) * 64 + dt * 16 + lm) * S_LEN
                              + k0 + quad * 8);

        // ---- PV-B: heads w*4+2, w*4+3 from vfB ----
#pragma unroll
        for (int h2 = 0; h2 < 2; ++h2) {
            f16x8 pa = *(const f16x8*)(P5 + (size_t)(w * 4 + 2 + h2) * 640
                                       + lm * 40 + quad * 8);
#pragma unroll
            for (int dt = 0; dt < 4; ++dt)
                oacc[2 + h2][dt] = __builtin_amdgcn_mfma_f32_16x16x32_f16(pa, vfB[h2][dt],
                                                                          oacc[2 + h2][dt], 0, 0, 0);
        }
    }

    __syncthreads();
    u16* Ol = smem;          // [16 q][1024 e] = 16384 u16 <= 19456 u16
#pragma unroll
    for (int h2 = 0; h2 < 4; ++h2) {
        const int h = w * 4 + h2;
#pragma unroll
        for (int dt = 0; dt < 4; ++dt)
#pragma unroll
            for (int rg = 0; rg < 4; ++rg)
                Ol[(quad * 4 + rg) * 1024 + h * 64 + dt * 16 + lm] = f2bf(oacc[h2][dt][rg]);
    }
    __syncthreads();
    u16* dst = (kq == 0) ? c0 : (kq == 1) ? c1 : (kq == 2) ? c2 : c3;
#pragma unroll
    for (int i2 = 0; i2 < 8; ++i2) {
        const int unit = i2 * 256 + t;
        const int r = unit >> 7, cu = unit & 127;
        *(bf16x8*)(dst + ((size_t)b * S_LEN + q0 + r) * E_DIM + cu * 8) =
            *(const bf16x8*)(Ol + r * 1024 + cu * 8);
    }
}

// ---------------------------------------------------------------------------
// Workspace overlay plan (56 MB total):
//   [xb 4M][W3 3M][Wob 1M][Qb 4M][Kb 4M][Vtb 4M][ctxA 4M][ctxB 4M]  (u16)
//   ctxC := xb    (dead after gemm_qkv)
//   ctxD := W3    (spans W3+Wob; Wo cvt DEFERRED until after combine)
// ---------------------------------------------------------------------------
extern "C" void kernel_launch(void* const* d_in, const int* in_sizes, int n_in,
                              void* d_out, int out_size, void* d_ws, size_t ws_size,
                              hipStream_t stream)
{
    const float* x  = (const float*)d_in[0];
    const float* Wq = (const float*)d_in[1];
    const float* bq = (const float*)d_in[2];
    const float* Wk = (const float*)d_in[3];
    const float* bk = (const float*)d_in[4];
    const float* Wv = (const float*)d_in[5];
    const float* bv = (const float*)d_in[6];
    const float* Wo = (const float*)d_in[7];
    const float* bo = (const float*)d_in[8];
    float* out = (float*)d_out;

    const size_t MAT = (size_t)M_ROWS * E_DIM;   // 4M elems
    const size_t WSZ = (size_t)E_DIM * E_DIM;    // 1M elems
    u16* xb   = (u16*)d_ws;
    u16* W3   = xb   + MAT;
    u16* Wob  = W3   + 3 * WSZ;
    u16* Qb   = Wob  + WSZ;
    u16* Kb   = Qb   + MAT;
    u16* Vtb  = Kb   + MAT;          // V transposed [b][e][s], FP16
    u16* ctxA = Vtb  + MAT;
    u16* ctxB = ctxA + MAT;
    u16* ctxC = xb;                  // overlay (dead after gemm_qkv)
    u16* ctxD = W3;                  // overlay (W3+Wob dead during attn)

    // 1) convert x + QKV weights to bf16 (Wo deferred; 2 launches not 5)
    cvt_bf16<<<(int)(MAT / 1024), 256, 0, stream>>>(x, xb, (int)MAT);
    dim3 wgrid(WSZ / 1024, 3);
    cvt_w3<<<wgrid, 256, 0, stream>>>(Wq, Wk, Wv, W3);

    // 2) fused QKV projection (Q pre-scaled, V fp16-transposed)
    dim3 qkvgrid(M_ROWS / 128, 3 * E_DIM / 128);   // 32 x 24 = 768 blocks
    gemm_qkv<<<qkvgrid, 256, 0, stream>>>(xb, W3, bq, bk, bv, Qb, Kb, Vtb);

    // 3) fused MFMA attention, KSPLIT=4, combo->XCD pinned, 3 waves/SIMD
    attn_v11<<<BATCH * 128 * KSPLIT, 256, 0, stream>>>(Qb, Kb, Vtb,
                                                       ctxA, ctxB, ctxC, ctxD);

    // 4) combine k-quarters (in place into ctxA)
    combine_ctx4<<<(int)(MAT / 1024), 256, 0, stream>>>(ctxA, ctxB, ctxC, ctxD,
                                                        ctxA, (int)MAT);

    // 5) Wo -> bf16 (deferred: its region doubled as ctxD during attn)
    cvt_bf16<<<(int)(WSZ / 1024), 256, 0, stream>>>(Wo, Wob, (int)WSZ);

    // 6) output projection (fp32 out)
    dim3 ogrid(M_ROWS / 128, E_DIM / 128);         // 32 x 8
    gemm_wo<<<ogrid, 256, 0, stream>>>(ctxA, Wob, bo, out);
}

// Round 10
// 333.891 us; speedup vs baseline: 1.3753x; 1.3753x over previous
//
#include <hip/hip_runtime.h>
#include <cstddef>
#include <cstdint>

// Problem: B=2, S=2048, E=1024, H=16, D=64.  Softmax over HEADS (ref quirk).
#define BATCH 2
#define S_LEN 2048
#define E_DIM 1024
#define NH    16
#define HD    64
#define M_ROWS (BATCH * S_LEN)   // 4096

// fold softmax scale into Q at projection time: 1/sqrt(64) * log2(e)
#define QSCALE 0.18033688011112042f

typedef unsigned short u16;
typedef short     bf16x8 __attribute__((ext_vector_type(8)));
typedef _Float16  f16x8  __attribute__((ext_vector_type(8)));
typedef __fp16    h16x2  __attribute__((ext_vector_type(2)));   // cvt_pkrtz return type
typedef float     f32x4  __attribute__((ext_vector_type(4)));

__device__ __forceinline__ u16 f2bf(float f) {
    union { float f; unsigned u; } v; v.f = f;
    unsigned r = v.u + 0x7fffu + ((v.u >> 16) & 1u);   // RNE
    return (u16)(r >> 16);
}
__device__ __forceinline__ float bf2f(u16 h) {
    union { unsigned u; float f; } v; v.u = ((unsigned)h) << 16;
    return v.f;
}

// async global->LDS DMA, 16 B per lane (global_load_lds_dwordx4).
__device__ __forceinline__ void load_lds16(const u16* g, u16* l) {
    __builtin_amdgcn_global_load_lds(
        (const __attribute__((address_space(1))) unsigned int*)g,
        (__attribute__((address_space(3))) unsigned int*)l, 16, 0, 0);
}

// ---------------------------------------------------------------------------
// fp32 -> bf16 bulk convert (n % 4 == 0)
// ---------------------------------------------------------------------------
__global__ void cvt_bf16(const float* __restrict__ in, u16* __restrict__ out, int n)
{
    int i = (blockIdx.x * 256 + threadIdx.x) * 4;
    if (i + 3 < n) {
        float4 v = *(const float4*)(in + i);
        u16 o[4] = { f2bf(v.x), f2bf(v.y), f2bf(v.z), f2bf(v.w) };
        *(uint2*)(out + i) = *(const uint2*)o;
    }
}

// three QKV weight matrices -> concat bf16 buffer, one launch (grid.y = seg)
__global__ void cvt_w3(const float* __restrict__ Wq, const float* __restrict__ Wk,
                       const float* __restrict__ Wv, u16* __restrict__ out)
{
    const int seg = blockIdx.y;
    const float* src = (seg == 0) ? Wq : (seg == 1) ? Wk : Wv;
    int i = (blockIdx.x * 256 + threadIdx.x) * 4;
    float4 v = *(const float4*)(src + i);
    u16 o[4] = { f2bf(v.x), f2bf(v.y), f2bf(v.z), f2bf(v.w) };
    *(uint2*)(out + (size_t)seg * E_DIM * E_DIM + i) = *(const uint2*)o;
}

// ---------------------------------------------------------------------------
// ctx = a + b  (bf16 in, fp32 add, bf16 out)
// ---------------------------------------------------------------------------
__global__ void combine_ctx(const u16* __restrict__ a, const u16* __restrict__ b,
                            u16* __restrict__ c, int n)
{
    int i = (blockIdx.x * 256 + threadIdx.x) * 4;
    if (i + 3 < n) {
        uint2 ua = *(const uint2*)(a + i);
        uint2 ub = *(const uint2*)(b + i);
        const u16* pa = (const u16*)&ua; const u16* pb = (const u16*)&ub;
        u16 o[4];
#pragma unroll
        for (int j = 0; j < 4; ++j) o[j] = f2bf(bf2f(pa[j]) + bf2f(pb[j]));
        *(uint2*)(c + i) = *(const uint2*)o;
    }
}

// ---------------------------------------------------------------------------
// Fused QKV projection GEMM (m97-style DMA staging).
//   seg 0 -> Q, bf16, PRE-SCALED by QSCALE (softmax scale folded in)
//   seg 1 -> K, bf16
//   seg 2 -> V, written TRANSPOSED Vt[b][e][s] in FP16 (PV runs fp16 MFMA)
// ---------------------------------------------------------------------------
__global__ __launch_bounds__(256)
void gemm_qkv(const u16* __restrict__ A, const u16* __restrict__ W3,
              const float* __restrict__ bq, const float* __restrict__ bk,
              const float* __restrict__ bv,
              u16* __restrict__ Qb, u16* __restrict__ Kb, u16* __restrict__ Vtb)
{
    __shared__ u16 Al[128 * 32];
    __shared__ u16 Bl[128 * 32];
    const int K = E_DIM;
    const int t = threadIdx.x;
    const int w = t >> 6, lane = t & 63;
    const int quad = lane >> 4, lm = lane & 15;
    const int wy = w >> 1, wx = w & 1;
    const int m0 = blockIdx.x * 128, n0 = blockIdx.y * 128;
    const int lrow  = lane >> 2;
    const int lcol8 = (lane & 3) * 8;

    f32x4 acc[4][4] = {};

    for (int kb = 0; kb < K; kb += 32) {
        __syncthreads();
#pragma unroll
        for (int i = 0; i < 2; ++i) {
            const int r0 = w * 32 + i * 16;
            load_lds16(A  + (size_t)(m0 + r0 + lrow) * K + kb + lcol8, &Al[r0 * 32]);
            load_lds16(W3 + (size_t)(n0 + r0 + lrow) * K + kb + lcol8, &Bl[r0 * 32]);
        }
        __syncthreads();

        bf16x8 af[4], bfr[4];
#pragma unroll
        for (int i = 0; i < 4; ++i)
            af[i] = *(const bf16x8*)(Al + (wy * 64 + i * 16 + lm) * 32 + quad * 8);
#pragma unroll
        for (int j = 0; j < 4; ++j)
            bfr[j] = *(const bf16x8*)(Bl + (wx * 64 + j * 16 + lm) * 32 + quad * 8);
#pragma unroll
        for (int i = 0; i < 4; ++i)
#pragma unroll
            for (int j = 0; j < 4; ++j)
                acc[i][j] = __builtin_amdgcn_mfma_f32_16x16x32_bf16(af[i], bfr[j], acc[i][j], 0, 0, 0);
    }

    const int seg = n0 >> 10;            // 0=Q, 1=K, 2=V
    const int nl0 = n0 & 1023;
    const float* bs = (seg == 0) ? bq : (seg == 1) ? bk : bv;

    if (seg < 2) {
        u16* dst = (seg == 0) ? Qb : Kb;
        const float scl = (seg == 0) ? QSCALE : 1.0f;
#pragma unroll
        for (int j = 0; j < 4; ++j) {
            const int n = nl0 + wx * 64 + j * 16 + lm;
            const float bias = bs[n];
#pragma unroll
            for (int i = 0; i < 4; ++i) {
                const int mrow = m0 + wy * 64 + i * 16 + quad * 4;
#pragma unroll
                for (int rg = 0; rg < 4; ++rg)
                    dst[(size_t)(mrow + rg) * E_DIM + n] = f2bf((acc[i][j][rg] + bias) * scl);
            }
        }
    } else {
        // V: fp16, transposed -> Vt[b][e][s]
#pragma unroll
        for (int j = 0; j < 4; ++j) {
            const int n = nl0 + wx * 64 + j * 16 + lm;
            const float bias = bs[n];
#pragma unroll
            for (int i = 0; i < 4; ++i) {
                const int mrow = m0 + wy * 64 + i * 16 + quad * 4;
                const int batch = mrow >> 11;
                const int sloc  = mrow & 2047;
                u16 o[4];
#pragma unroll
                for (int rg = 0; rg < 4; ++rg) {
                    union { _Float16 h; u16 u; } cv;
                    cv.h = (_Float16)(acc[i][j][rg] + bias);
                    o[rg] = cv.u;
                }
                *(uint2*)&Vtb[(size_t)batch * E_DIM * S_LEN + (size_t)n * S_LEN + sloc]
                    = *(const uint2*)o;
            }
        }
    }
}

// ---------------------------------------------------------------------------
// Output projection GEMM — unchanged.
// ---------------------------------------------------------------------------
__global__ __launch_bounds__(256)
void gemm_wo(const u16* __restrict__ A, const u16* __restrict__ B,
             const float* __restrict__ bias, float* __restrict__ C)
{
    __shared__ u16 Al[128 * 32];
    __shared__ u16 Bl[128 * 32];
    const int K = E_DIM, N = E_DIM;
    const int t = threadIdx.x;
    const int w = t >> 6, lane = t & 63;
    const int quad = lane >> 4, lm = lane & 15;
    const int wy = w >> 1, wx = w & 1;
    const int m0 = blockIdx.x * 128, n0 = blockIdx.y * 128;
    const int lrow  = lane >> 2;
    const int lcol8 = (lane & 3) * 8;

    f32x4 acc[4][4] = {};

    for (int kb = 0; kb < K; kb += 32) {
        __syncthreads();
#pragma unroll
        for (int i = 0; i < 2; ++i) {
            const int r0 = w * 32 + i * 16;
            load_lds16(A + (size_t)(m0 + r0 + lrow) * K + kb + lcol8, &Al[r0 * 32]);
            load_lds16(B + (size_t)(n0 + r0 + lrow) * K + kb + lcol8, &Bl[r0 * 32]);
        }
        __syncthreads();

        bf16x8 af[4], bfr[4];
#pragma unroll
        for (int i = 0; i < 4; ++i)
            af[i] = *(const bf16x8*)(Al + (wy * 64 + i * 16 + lm) * 32 + quad * 8);
#pragma unroll
        for (int j = 0; j < 4; ++j)
            bfr[j] = *(const bf16x8*)(Bl + (wx * 64 + j * 16 + lm) * 32 + quad * 8);
#pragma unroll
        for (int i = 0; i < 4; ++i)
#pragma unroll
            for (int j = 0; j < 4; ++j)
                acc[i][j] = __builtin_amdgcn_mfma_f32_16x16x32_bf16(af[i], bfr[j], acc[i][j], 0, 0, 0);
    }

#pragma unroll
    for (int j = 0; j < 4; ++j) {
        const int n = n0 + wx * 64 + j * 16 + lm;
        const float bs = bias[n];
#pragma unroll
        for (int i = 0; i < 4; ++i) {
            const int mrow = m0 + wy * 64 + i * 16 + quad * 4;
#pragma unroll
            for (int rg = 0; rg < 4; ++rg)
                C[(size_t)(mrow + rg) * N + n] = acc[i][j][rg] + bs;
        }
    }
}

// ---------------------------------------------------------------------------
// attn_v12: L2-traffic amortization (R9 insight: kernel is L2-BW bound,
// 2 GB L2 reads/dispatch; occupancy quantized at 256-reg -> 2 waves/SIMD
// is a hard floor for this working set).
//   512 threads / 8 waves per block; wave w owns heads {2w, 2w+1} and
//   computes BOTH 16-q subtiles (32 q per block).  K and V loads are
//   q-independent -> per-block load bytes unchanged while q served
//   doubles: L2 traffic 2 GB -> 1 GB.  vf regs reused across subtiles.
//   KSPLIT=2, combo -> XCD-pair pinning, grid 256 = 1 block/CU, 1 pass.
//   Regs: qf32 + vf32 + oacc64 + transients ~ 190 <= 256 quantum.
//   LDS: S4h [1024 slots][18] = 36.9 KB, P5 [16h][32q][40] = 40 KB.
// ---------------------------------------------------------------------------
__global__ __launch_bounds__(512, 2)
void attn_v12(const u16* __restrict__ Q, const u16* __restrict__ K,
              const u16* __restrict__ Vt, u16* __restrict__ ctxA,
              u16* __restrict__ ctxB)
{
    __shared__ __align__(16) u16 smem[38912];   // 77824 B
    u16* S4h = smem;                 // [1024 slots][18] fp16 halves = 36864 B
    u16* P5  = smem + 18432;         // [16h][32q][40] halves       = 40960 B

    const int t     = threadIdx.x;   // 0..511
    const int w     = t >> 6;        // 0..7
    const int lane  = t & 63;
    const int quad  = lane >> 4, lm = lane & 15;

    // combo -> XCD-pair pinning (model: XCD = blockIdx % 8).
    const int i     = blockIdx.x;        // 0..255
    const int xcd   = i & 7;
    const int combo = xcd >> 1;          // 0..3
    const int b     = combo >> 1;
    const int khalf = combo & 1;
    const int slot  = i >> 3;            // 0..31
    const int qt    = ((xcd & 1) << 5) | slot;   // 0..63
    const int q0    = qt * 32;

    const size_t qbase = ((size_t)b * S_LEN + q0) * E_DIM;
    const size_t kmat  = (size_t)b * S_LEN * E_DIM;
    const size_t vtb   = (size_t)b * E_DIM * S_LEN;

    const int h0 = 2 * w;                // this wave's first head

    // Q fragments: [subtile][head-pair][hf], loop-invariant (32 regs)
    bf16x8 qf[2][2][2];
#pragma unroll
    for (int s = 0; s < 2; ++s)
#pragma unroll
        for (int hp = 0; hp < 2; ++hp)
#pragma unroll
            for (int hf = 0; hf < 2; ++hf)
                qf[s][hp][hf] = *(const bf16x8*)(Q + qbase
                                + (size_t)(s * 16 + lm) * E_DIM
                                + (h0 + hp) * 64 + hf * 32 + quad * 8);

    f32x4 oacc[2][2][4] = {};   // [hp][subtile][dtile] = 64 regs
    const int kbeg = khalf * (S_LEN / 2);
    const int sq = t & 31, sj = t >> 5;  // softmax: q=sq, k in {2sj, 2sj+1}

    for (int c = 0; c < (S_LEN / 2) / 32; ++c) {   // 32 chunks
        const int k0 = kbeg + c * 32;

        // ---- swapped QK^T: S[k][q] for 2 heads x 2 subtiles ----
        // K loaded ONCE per (hp,kt); reused for both subtiles.
        f32x4 sacc[2][2][2];   // [hp][kt][s]
#pragma unroll
        for (int hp = 0; hp < 2; ++hp)
#pragma unroll
            for (int kt = 0; kt < 2; ++kt) {
                bf16x8 kf0 = *(const bf16x8*)(K + kmat
                             + (size_t)(k0 + kt * 16 + lm) * E_DIM
                             + (h0 + hp) * 64 + quad * 8);
                bf16x8 kf1 = *(const bf16x8*)(K + kmat
                             + (size_t)(k0 + kt * 16 + lm) * E_DIM
                             + (h0 + hp) * 64 + 32 + quad * 8);
#pragma unroll
                for (int s = 0; s < 2; ++s) {
                    f32x4 sf = {};
                    sf = __builtin_amdgcn_mfma_f32_16x16x32_bf16(kf0, qf[s][hp][0], sf, 0, 0, 0);
                    sf = __builtin_amdgcn_mfma_f32_16x16x32_bf16(kf1, qf[s][hp][1], sf, 0, 0, 0);
                    sacc[hp][kt][s] = sf;
                }
            }

        // ---- pack head-pair per (k,q) slot -> fp16 u32 store each ----
        // (no barrier needed: all waves' S4h reads retired at prev B3)
#pragma unroll
        for (int kt = 0; kt < 2; ++kt)
#pragma unroll
            for (int s = 0; s < 2; ++s)
#pragma unroll
                for (int rg = 0; rg < 4; ++rg) {
                    union { h16x2 v; unsigned u; } pk;
                    pk.v = __builtin_amdgcn_cvt_pkrtz(sacc[0][kt][s][rg],
                                                      sacc[1][kt][s][rg]);
                    const int kl = kt * 16 + quad * 4 + rg;
                    *(unsigned*)(S4h + (size_t)(kl * 32 + s * 16 + lm) * 18 + 2 * w) = pk.u;
                }

        // ---- V prefetch (q-independent: serves BOTH subtiles) ----
        f16x8 vf[2][4];
#pragma unroll
        for (int hp = 0; hp < 2; ++hp)
#pragma unroll
            for (int dt = 0; dt < 4; ++dt)
                vf[hp][dt] = *(const f16x8*)(Vt + vtb
                             + (size_t)((h0 + hp) * 64 + dt * 16 + lm) * S_LEN
                             + k0 + quad * 8);

        asm volatile("s_waitcnt lgkmcnt(0)" ::: "memory");
        __builtin_amdgcn_s_barrier();   // B2: S4h visible everywhere

        // ---- register softmax over heads: 2 (k,q) slots per thread ----
#pragma unroll
        for (int ks = 0; ks < 2; ++ks) {
            const u16* base = S4h + (size_t)((2 * sj + ks) * 32 + sq) * 18;
            union { uint4 u; __fp16 h[8]; } r0, r1;
            r0.u = *(const uint4*)(base);
            r1.u = *(const uint4*)(base + 8);
            float s[16];
#pragma unroll
            for (int z = 0; z < 8; ++z) {
                s[z]     = (float)r0.h[z];
                s[8 + z] = (float)r1.h[z];
            }
            float m = s[0];
#pragma unroll
            for (int h = 1; h < 16; ++h) m = fmaxf(m, s[h]);
            float sum = 0.f;
#pragma unroll
            for (int h = 0; h < 16; ++h) {
                s[h] = __builtin_amdgcn_exp2f(s[h] - m);  // scale folded into Q
                sum += s[h];
            }
            const float inv = __builtin_amdgcn_rcpf(sum);
#pragma unroll
            for (int h = 0; h < 16; ++h) {
                union { __fp16 hv; u16 u; } cv;
                cv.hv = (__fp16)(s[h] * inv);
                P5[(size_t)h * 1280 + sq * 40 + 2 * sj + ks] = cv.u;
            }
        }

        asm volatile("s_waitcnt lgkmcnt(0)" ::: "memory");
        __builtin_amdgcn_s_barrier();   // B3: P5 visible; all S4h/P5 reads retired

        // ---- PV: 2 heads x 2 subtiles, V regs shared across subtiles ----
#pragma unroll
        for (int hp = 0; hp < 2; ++hp)
#pragma unroll
            for (int s = 0; s < 2; ++s) {
                f16x8 pa = *(const f16x8*)(P5 + (size_t)(h0 + hp) * 1280
                                           + (s * 16 + lm) * 40 + quad * 8);
#pragma unroll
                for (int dt = 0; dt < 4; ++dt)
                    oacc[hp][s][dt] = __builtin_amdgcn_mfma_f32_16x16x32_f16(
                                          pa, vf[hp][dt], oacc[hp][s][dt], 0, 0, 0);
            }
    }

    __syncthreads();
    u16* Ol = smem;          // [32 q][1024 e] = 32768 u16 <= 38912 u16
#pragma unroll
    for (int hp = 0; hp < 2; ++hp) {
        const int h = h0 + hp;
#pragma unroll
        for (int s = 0; s < 2; ++s)
#pragma unroll
            for (int dt = 0; dt < 4; ++dt)
#pragma unroll
                for (int rg = 0; rg < 4; ++rg)
                    Ol[(size_t)(s * 16 + quad * 4 + rg) * 1024 + h * 64 + dt * 16 + lm]
                        = f2bf(oacc[hp][s][dt][rg]);
    }
    __syncthreads();
    u16* dst = khalf ? ctxB : ctxA;
#pragma unroll
    for (int i2 = 0; i2 < 8; ++i2) {
        const int unit = i2 * 512 + t;
        const int r = unit >> 7, cu = unit & 127;   // r 0..31
        *(bf16x8*)(dst + ((size_t)b * S_LEN + q0 + r) * E_DIM + cu * 8) =
            *(const bf16x8*)(Ol + (size_t)r * 1024 + cu * 8);
    }
}

// ---------------------------------------------------------------------------
extern "C" void kernel_launch(void* const* d_in, const int* in_sizes, int n_in,
                              void* d_out, int out_size, void* d_ws, size_t ws_size,
                              hipStream_t stream)
{
    const float* x  = (const float*)d_in[0];
    const float* Wq = (const float*)d_in[1];
    const float* bq = (const float*)d_in[2];
    const float* Wk = (const float*)d_in[3];
    const float* bk = (const float*)d_in[4];
    const float* Wv = (const float*)d_in[5];
    const float* bv = (const float*)d_in[6];
    const float* Wo = (const float*)d_in[7];
    const float* bo = (const float*)d_in[8];
    float* out = (float*)d_out;

    // bf16/fp16 workspace (u16 elems), 56 MB:
    const size_t MAT = (size_t)M_ROWS * E_DIM;   // 4M elems
    const size_t WSZ = (size_t)E_DIM * E_DIM;    // 1M elems
    u16* xb   = (u16*)d_ws;          // x; later combined ctx
    u16* W3   = xb   + MAT;          // Wq|Wk|Wv concat [3072][1024]
    u16* Wob  = W3   + 3 * WSZ;
    u16* Qb   = Wob  + WSZ;
    u16* Kb   = Qb   + MAT;
    u16* Vtb  = Kb   + MAT;          // V transposed [b][e][s], FP16
    u16* ctxA = Vtb  + MAT;
    u16* ctxB = ctxA + MAT;

    // 1) convert inputs to bf16 (QKV weights in one merged launch)
    cvt_bf16<<<(int)(MAT / 1024), 256, 0, stream>>>(x, xb, (int)MAT);
    dim3 wgrid(WSZ / 1024, 3);
    cvt_w3<<<wgrid, 256, 0, stream>>>(Wq, Wk, Wv, W3);
    cvt_bf16<<<(int)(WSZ / 1024), 256, 0, stream>>>(Wo, Wob, (int)WSZ);

    // 2) fused QKV projection (Q pre-scaled, V fp16-transposed)
    dim3 qkvgrid(M_ROWS / 128, 3 * E_DIM / 128);   // 32 x 24 = 768 blocks
    gemm_qkv<<<qkvgrid, 256, 0, stream>>>(xb, W3, bq, bk, bv, Qb, Kb, Vtb);

    // 3) fused MFMA attention: 32 q/block, 512 thr, KSPLIT=2, XCD-pinned,
    //    grid 256 = 1 block/CU, single residency pass
    attn_v12<<<BATCH * 64 * 2, 512, 0, stream>>>(Qb, Kb, Vtb, ctxA, ctxB);

    // 4) combine k-halves into xb (x is dead)
    combine_ctx<<<(int)(MAT / 1024), 256, 0, stream>>>(ctxA, ctxB, xb, (int)MAT);

    // 5) output projection (fp32 out)
    dim3 ogrid(M_ROWS / 128, E_DIM / 128);         // 32 x 8
    gemm_wo<<<ogrid, 256, 0, stream>>>(xb, Wob, bo, out);
}

// Round 11
// 323.372 us; speedup vs baseline: 1.4201x; 1.0325x over previous
//
#include <hip/hip_runtime.h>
#include <cstddef>
#include <cstdint>

// Problem: B=2, S=2048, E=1024, H=16, D=64.  Softmax over HEADS (ref quirk).
#define BATCH 2
#define S_LEN 2048
#define E_DIM 1024
#define NH    16
#define HD    64
#define M_ROWS (BATCH * S_LEN)   // 4096

// fold softmax scale into Q at projection time: 1/sqrt(64) * log2(e)
#define QSCALE 0.18033688011112042f

typedef unsigned short u16;
typedef short     bf16x8 __attribute__((ext_vector_type(8)));
typedef _Float16  f16x8  __attribute__((ext_vector_type(8)));
typedef __fp16    h16x2  __attribute__((ext_vector_type(2)));   // cvt_pkrtz return type
typedef float     f32x4  __attribute__((ext_vector_type(4)));

__device__ __forceinline__ u16 f2bf(float f) {
    union { float f; unsigned u; } v; v.f = f;
    unsigned r = v.u + 0x7fffu + ((v.u >> 16) & 1u);   // RNE
    return (u16)(r >> 16);
}
__device__ __forceinline__ float bf2f(u16 h) {
    union { unsigned u; float f; } v; v.u = ((unsigned)h) << 16;
    return v.f;
}

// async global->LDS DMA, 16 B per lane (global_load_lds_dwordx4).
__device__ __forceinline__ void load_lds16(const u16* g, u16* l) {
    __builtin_amdgcn_global_load_lds(
        (const __attribute__((address_space(1))) unsigned int*)g,
        (__attribute__((address_space(3))) unsigned int*)l, 16, 0, 0);
}

// ---------------------------------------------------------------------------
// fp32 -> bf16 bulk convert (n % 4 == 0)
// ---------------------------------------------------------------------------
__global__ void cvt_bf16(const float* __restrict__ in, u16* __restrict__ out, int n)
{
    int i = (blockIdx.x * 256 + threadIdx.x) * 4;
    if (i + 3 < n) {
        float4 v = *(const float4*)(in + i);
        u16 o[4] = { f2bf(v.x), f2bf(v.y), f2bf(v.z), f2bf(v.w) };
        *(uint2*)(out + i) = *(const uint2*)o;
    }
}

// three QKV weight matrices -> concat bf16 buffer, one launch (grid.y = seg)
__global__ void cvt_w3(const float* __restrict__ Wq, const float* __restrict__ Wk,
                       const float* __restrict__ Wv, u16* __restrict__ out)
{
    const int seg = blockIdx.y;
    const float* src = (seg == 0) ? Wq : (seg == 1) ? Wk : Wv;
    int i = (blockIdx.x * 256 + threadIdx.x) * 4;
    float4 v = *(const float4*)(src + i);
    u16 o[4] = { f2bf(v.x), f2bf(v.y), f2bf(v.z), f2bf(v.w) };
    *(uint2*)(out + (size_t)seg * E_DIM * E_DIM + i) = *(const uint2*)o;
}

// ---------------------------------------------------------------------------
// ctx = a + b  (bf16 in, fp32 add, bf16 out)
// ---------------------------------------------------------------------------
__global__ void combine_ctx(const u16* __restrict__ a, const u16* __restrict__ b,
                            u16* __restrict__ c, int n)
{
    int i = (blockIdx.x * 256 + threadIdx.x) * 4;
    if (i + 3 < n) {
        uint2 ua = *(const uint2*)(a + i);
        uint2 ub = *(const uint2*)(b + i);
        const u16* pa = (const u16*)&ua; const u16* pb = (const u16*)&ub;
        u16 o[4];
#pragma unroll
        for (int j = 0; j < 4; ++j) o[j] = f2bf(bf2f(pa[j]) + bf2f(pb[j]));
        *(uint2*)(c + i) = *(const uint2*)o;
    }
}

// ---------------------------------------------------------------------------
// Fused QKV projection GEMM (m97-style DMA staging).
//   seg 0 -> Q, bf16, PRE-SCALED by QSCALE (softmax scale folded in)
//   seg 1 -> K, bf16
//   seg 2 -> V, written TRANSPOSED Vt[b][e][s] in FP16 (PV runs fp16 MFMA)
// ---------------------------------------------------------------------------
__global__ __launch_bounds__(256)
void gemm_qkv(const u16* __restrict__ A, const u16* __restrict__ W3,
              const float* __restrict__ bq, const float* __restrict__ bk,
              const float* __restrict__ bv,
              u16* __restrict__ Qb, u16* __restrict__ Kb, u16* __restrict__ Vtb)
{
    __shared__ u16 Al[128 * 32];
    __shared__ u16 Bl[128 * 32];
    const int K = E_DIM;
    const int t = threadIdx.x;
    const int w = t >> 6, lane = t & 63;
    const int quad = lane >> 4, lm = lane & 15;
    const int wy = w >> 1, wx = w & 1;
    const int m0 = blockIdx.x * 128, n0 = blockIdx.y * 128;
    const int lrow  = lane >> 2;
    const int lcol8 = (lane & 3) * 8;

    f32x4 acc[4][4] = {};

    for (int kb = 0; kb < K; kb += 32) {
        __syncthreads();
#pragma unroll
        for (int i = 0; i < 2; ++i) {
            const int r0 = w * 32 + i * 16;
            load_lds16(A  + (size_t)(m0 + r0 + lrow) * K + kb + lcol8, &Al[r0 * 32]);
            load_lds16(W3 + (size_t)(n0 + r0 + lrow) * K + kb + lcol8, &Bl[r0 * 32]);
        }
        __syncthreads();

        bf16x8 af[4], bfr[4];
#pragma unroll
        for (int i = 0; i < 4; ++i)
            af[i] = *(const bf16x8*)(Al + (wy * 64 + i * 16 + lm) * 32 + quad * 8);
#pragma unroll
        for (int j = 0; j < 4; ++j)
            bfr[j] = *(const bf16x8*)(Bl + (wx * 64 + j * 16 + lm) * 32 + quad * 8);
#pragma unroll
        for (int i = 0; i < 4; ++i)
#pragma unroll
            for (int j = 0; j < 4; ++j)
                acc[i][j] = __builtin_amdgcn_mfma_f32_16x16x32_bf16(af[i], bfr[j], acc[i][j], 0, 0, 0);
    }

    const int seg = n0 >> 10;            // 0=Q, 1=K, 2=V
    const int nl0 = n0 & 1023;
    const float* bs = (seg == 0) ? bq : (seg == 1) ? bk : bv;

    if (seg < 2) {
        u16* dst = (seg == 0) ? Qb : Kb;
        const float scl = (seg == 0) ? QSCALE : 1.0f;
#pragma unroll
        for (int j = 0; j < 4; ++j) {
            const int n = nl0 + wx * 64 + j * 16 + lm;
            const float bias = bs[n];
#pragma unroll
            for (int i = 0; i < 4; ++i) {
                const int mrow = m0 + wy * 64 + i * 16 + quad * 4;
#pragma unroll
                for (int rg = 0; rg < 4; ++rg)
                    dst[(size_t)(mrow + rg) * E_DIM + n] = f2bf((acc[i][j][rg] + bias) * scl);
            }
        }
    } else {
        // V: fp16, transposed -> Vt[b][e][s]
#pragma unroll
        for (int j = 0; j < 4; ++j) {
            const int n = nl0 + wx * 64 + j * 16 + lm;
            const float bias = bs[n];
#pragma unroll
            for (int i = 0; i < 4; ++i) {
                const int mrow = m0 + wy * 64 + i * 16 + quad * 4;
                const int batch = mrow >> 11;
                const int sloc  = mrow & 2047;
                u16 o[4];
#pragma unroll
                for (int rg = 0; rg < 4; ++rg) {
                    union { _Float16 h; u16 u; } cv;
                    cv.h = (_Float16)(acc[i][j][rg] + bias);
                    o[rg] = cv.u;
                }
                *(uint2*)&Vtb[(size_t)batch * E_DIM * S_LEN + (size_t)n * S_LEN + sloc]
                    = *(const uint2*)o;
            }
        }
    }
}

// ---------------------------------------------------------------------------
// Output projection GEMM — unchanged.
// ---------------------------------------------------------------------------
__global__ __launch_bounds__(256)
void gemm_wo(const u16* __restrict__ A, const u16* __restrict__ B,
             const float* __restrict__ bias, float* __restrict__ C)
{
    __shared__ u16 Al[128 * 32];
    __shared__ u16 Bl[128 * 32];
    const int K = E_DIM, N = E_DIM;
    const int t = threadIdx.x;
    const int w = t >> 6, lane = t & 63;
    const int quad = lane >> 4, lm = lane & 15;
    const int wy = w >> 1, wx = w & 1;
    const int m0 = blockIdx.x * 128, n0 = blockIdx.y * 128;
    const int lrow  = lane >> 2;
    const int lcol8 = (lane & 3) * 8;

    f32x4 acc[4][4] = {};

    for (int kb = 0; kb < K; kb += 32) {
        __syncthreads();
#pragma unroll
        for (int i = 0; i < 2; ++i) {
            const int r0 = w * 32 + i * 16;
            load_lds16(A + (size_t)(m0 + r0 + lrow) * K + kb + lcol8, &Al[r0 * 32]);
            load_lds16(B + (size_t)(n0 + r0 + lrow) * K + kb + lcol8, &Bl[r0 * 32]);
        }
        __syncthreads();

        bf16x8 af[4], bfr[4];
#pragma unroll
        for (int i = 0; i < 4; ++i)
            af[i] = *(const bf16x8*)(Al + (wy * 64 + i * 16 + lm) * 32 + quad * 8);
#pragma unroll
        for (int j = 0; j < 4; ++j)
            bfr[j] = *(const bf16x8*)(Bl + (wx * 64 + j * 16 + lm) * 32 + quad * 8);
#pragma unroll
        for (int i = 0; i < 4; ++i)
#pragma unroll
            for (int j = 0; j < 4; ++j)
                acc[i][j] = __builtin_amdgcn_mfma_f32_16x16x32_bf16(af[i], bfr[j], acc[i][j], 0, 0, 0);
    }

#pragma unroll
    for (int j = 0; j < 4; ++j) {
        const int n = n0 + wx * 64 + j * 16 + lm;
        const float bs = bias[n];
#pragma unroll
        for (int i = 0; i < 4; ++i) {
            const int mrow = m0 + wy * 64 + i * 16 + quad * 4;
#pragma unroll
            for (int rg = 0; rg < 4; ++rg)
                C[(size_t)(mrow + rg) * N + n] = acc[i][j][rg] + bs;
        }
    }
}

// ---------------------------------------------------------------------------
// attn_v13 = v12 (32 q/block, 512 thr, KSPLIT=2, XCD-pinned) with:
//   (1) 64-k chunks: 16 chunks, 2 barriers each (barriers/k halved; phases
//       2x longer -> latency amortized).  LDS 147 KB (1 block/CU as before).
//   (2) S4h rotate-by-quad: physical q-slot = (qv + 8*quad)&31 at odd dword
//       pitch 9 -> write banks = 9*qphys over full 0..31 range, 2 lanes/bank
//       = FREE (was 4-way: kl*32*9 = 0 mod 32 killed the quad spread).
//       Reader recomputes rotation from k: all 4 of a thread's k share
//       (k>>2)&3 = sj&3.
//   (3) paired P5 writes (u32 per head per k-pair) + tree max/sum.
//   V in 2 windows of 32 regs (A before B2, B between PV halves) to keep
//   the register peak in the 256-quantum.  All arrays statically indexed.
// ---------------------------------------------------------------------------
__global__ __launch_bounds__(512, 2)
void attn_v13(const u16* __restrict__ Q, const u16* __restrict__ K,
              const u16* __restrict__ Vt, u16* __restrict__ ctxA,
              u16* __restrict__ ctxB)
{
    __shared__ __align__(16) u16 smem[73728];   // 147456 B
    u16* S4h = smem;                  // [2048 slots][18] fp16 halves = 73728 B
    u16* P5  = smem + 36864;          // [16h][32q][72] halves        = 73728 B

    const int t     = threadIdx.x;   // 0..511
    const int w     = t >> 6;        // 0..7
    const int lane  = t & 63;
    const int quad  = lane >> 4, lm = lane & 15;

    // combo -> XCD-pair pinning (model: XCD = blockIdx % 8).
    const int i     = blockIdx.x;        // 0..255
    const int xcd   = i & 7;
    const int combo = xcd >> 1;          // 0..3
    const int b     = combo >> 1;
    const int khalf = combo & 1;
    const int slot  = i >> 3;            // 0..31
    const int qt    = ((xcd & 1) << 5) | slot;   // 0..63
    const int q0    = qt * 32;

    const size_t qbase = ((size_t)b * S_LEN + q0) * E_DIM;
    const size_t kmat  = (size_t)b * S_LEN * E_DIM;
    const size_t vtb   = (size_t)b * E_DIM * S_LEN;

    const int h0 = 2 * w;                // this wave's first head

    // Q fragments: [subtile][head-pair][hf], loop-invariant (32 regs)
    bf16x8 qf[2][2][2];
#pragma unroll
    for (int s = 0; s < 2; ++s)
#pragma unroll
        for (int hp = 0; hp < 2; ++hp)
#pragma unroll
            for (int hf = 0; hf < 2; ++hf)
                qf[s][hp][hf] = *(const bf16x8*)(Q + qbase
                                + (size_t)(s * 16 + lm) * E_DIM
                                + (h0 + hp) * 64 + hf * 32 + quad * 8);

    f32x4 oacc[2][2][4] = {};   // [hp][subtile][dtile] = 64 acc regs
    const int kbeg = khalf * (S_LEN / 2);
    const int sq = t & 31, sj = t >> 5;  // softmax: q=sq, k in {4sj..4sj+3}
    const int qrot = (sq + 8 * (sj & 3)) & 31;   // reader-side rotated q-slot

    for (int c = 0; c < (S_LEN / 2) / 64; ++c) {   // 16 chunks of 64 k
        const int k0 = kbeg + c * 64;

        // ---- swapped QK^T: 4 kt-groups, pack each immediately ----
#pragma unroll
        for (int kt = 0; kt < 4; ++kt) {
            f32x4 sacc[2][2];   // [hp][s], transient per kt
#pragma unroll
            for (int hp = 0; hp < 2; ++hp) {
                bf16x8 kf0 = *(const bf16x8*)(K + kmat
                             + (size_t)(k0 + kt * 16 + lm) * E_DIM
                             + (h0 + hp) * 64 + quad * 8);
                bf16x8 kf1 = *(const bf16x8*)(K + kmat
                             + (size_t)(k0 + kt * 16 + lm) * E_DIM
                             + (h0 + hp) * 64 + 32 + quad * 8);
#pragma unroll
                for (int s = 0; s < 2; ++s) {
                    f32x4 sf = {};
                    sf = __builtin_amdgcn_mfma_f32_16x16x32_bf16(kf0, qf[s][hp][0], sf, 0, 0, 0);
                    sf = __builtin_amdgcn_mfma_f32_16x16x32_bf16(kf1, qf[s][hp][1], sf, 0, 0, 0);
                    sacc[hp][s] = sf;
                }
            }
            // pack head-pair, rotate-by-quad slot (write banks FREE)
#pragma unroll
            for (int s = 0; s < 2; ++s)
#pragma unroll
                for (int rg = 0; rg < 4; ++rg) {
                    union { h16x2 v; unsigned u; } pk;
                    pk.v = __builtin_amdgcn_cvt_pkrtz(sacc[0][s][rg], sacc[1][s][rg]);
                    const int kl  = kt * 16 + quad * 4 + rg;          // 0..63
                    const int qph = ((s * 16 + lm) + 8 * quad) & 31;  // rotated
                    *(unsigned*)(S4h + (size_t)(kl * 32 + qph) * 18 + 2 * w) = pk.u;
                }
        }

        // ---- V window A (k0..k0+31), serves both subtiles ----
        f16x8 vf[2][4];
#pragma unroll
        for (int hp = 0; hp < 2; ++hp)
#pragma unroll
            for (int dt = 0; dt < 4; ++dt)
                vf[hp][dt] = *(const f16x8*)(Vt + vtb
                             + (size_t)((h0 + hp) * 64 + dt * 16 + lm) * S_LEN
                             + k0 + quad * 8);

        asm volatile("s_waitcnt lgkmcnt(0)" ::: "memory");
        __builtin_amdgcn_s_barrier();   // B2: S4h visible everywhere

        // ---- register softmax over heads: 4 slots as 2 pairs ----
#pragma unroll
        for (int p = 0; p < 2; ++p) {
            float pv0[16], pv1[16];
#pragma unroll
            for (int e = 0; e < 2; ++e) {
                const int k = 4 * sj + 2 * p + e;                 // chunk-local
                const u16* base = S4h + (size_t)(k * 32 + qrot) * 18;
                union { uint4 u; __fp16 h[8]; } r0, r1;
                r0.u = *(const uint4*)(base);
                r1.u = *(const uint4*)(base + 8);
                float s[16];
#pragma unroll
                for (int z = 0; z < 8; ++z) {
                    s[z]     = (float)r0.h[z];
                    s[8 + z] = (float)r1.h[z];
                }
                // tree max (enables v_max3, depth ~4 vs 15-chain)
                const float m =
                    fmaxf(fmaxf(fmaxf(fmaxf(s[0], s[1]), fmaxf(s[2], s[3])),
                                fmaxf(fmaxf(s[4], s[5]), fmaxf(s[6], s[7]))),
                          fmaxf(fmaxf(fmaxf(s[8], s[9]), fmaxf(s[10], s[11])),
                                fmaxf(fmaxf(s[12], s[13]), fmaxf(s[14], s[15]))));
#pragma unroll
                for (int h = 0; h < 16; ++h)
                    s[h] = __builtin_amdgcn_exp2f(s[h] - m);   // scale folded into Q
                // tree sum
                const float sum =
                    (((s[0] + s[1]) + (s[2] + s[3])) + ((s[4] + s[5]) + (s[6] + s[7]))) +
                    (((s[8] + s[9]) + (s[10] + s[11])) + ((s[12] + s[13]) + (s[14] + s[15])));
                const float inv = __builtin_amdgcn_rcpf(sum);
                if (e == 0) {
#pragma unroll
                    for (int h = 0; h < 16; ++h) pv0[h] = s[h] * inv;
                } else {
#pragma unroll
                    for (int h = 0; h < 16; ++h) pv1[h] = s[h] * inv;
                }
            }
            // paired fp16 write: one u32 per head covers k-pair
#pragma unroll
            for (int h = 0; h < 16; ++h) {
                union { h16x2 v; unsigned u; } cv;
                cv.v = __builtin_amdgcn_cvt_pkrtz(pv0[h], pv1[h]);
                *(unsigned*)(P5 + (size_t)h * 2304 + sq * 72 + 4 * sj + 2 * p) = cv.u;
            }
        }

        asm volatile("s_waitcnt lgkmcnt(0)" ::: "memory");
        __builtin_amdgcn_s_barrier();   // B3: P5 visible; all S4h/P5 reads retired

        // ---- PV window A (k0..k0+31) ----
#pragma unroll
        for (int hp = 0; hp < 2; ++hp)
#pragma unroll
            for (int s = 0; s < 2; ++s) {
                f16x8 pa = *(const f16x8*)(P5 + (size_t)(h0 + hp) * 2304
                                           + (s * 16 + lm) * 72 + quad * 8);
#pragma unroll
                for (int dt = 0; dt < 4; ++dt)
                    oacc[hp][s][dt] = __builtin_amdgcn_mfma_f32_16x16x32_f16(
                                          pa, vf[hp][dt], oacc[hp][s][dt], 0, 0, 0);
            }

        // ---- V window B (k0+32..k0+63), reuses vf registers ----
#pragma unroll
        for (int hp = 0; hp < 2; ++hp)
#pragma unroll
            for (int dt = 0; dt < 4; ++dt)
                vf[hp][dt] = *(const f16x8*)(Vt + vtb
                             + (size_t)((h0 + hp) * 64 + dt * 16 + lm) * S_LEN
                             + k0 + 32 + quad * 8);

        // ---- PV window B ----
#pragma unroll
        for (int hp = 0; hp < 2; ++hp)
#pragma unroll
            for (int s = 0; s < 2; ++s) {
                f16x8 pa = *(const f16x8*)(P5 + (size_t)(h0 + hp) * 2304
                                           + (s * 16 + lm) * 72 + 32 + quad * 8);
#pragma unroll
                for (int dt = 0; dt < 4; ++dt)
                    oacc[hp][s][dt] = __builtin_amdgcn_mfma_f32_16x16x32_f16(
                                          pa, vf[hp][dt], oacc[hp][s][dt], 0, 0, 0);
            }
    }

    __syncthreads();
    u16* Ol = smem;          // [32 q][1024 e] = 32768 u16 <= 73728 u16
#pragma unroll
    for (int hp = 0; hp < 2; ++hp) {
        const int h = h0 + hp;
#pragma unroll
        for (int s = 0; s < 2; ++s)
#pragma unroll
            for (int dt = 0; dt < 4; ++dt)
#pragma unroll
                for (int rg = 0; rg < 4; ++rg)
                    Ol[(size_t)(s * 16 + quad * 4 + rg) * 1024 + h * 64 + dt * 16 + lm]
                        = f2bf(oacc[hp][s][dt][rg]);
    }
    __syncthreads();
    u16* dst = khalf ? ctxB : ctxA;
#pragma unroll
    for (int i2 = 0; i2 < 8; ++i2) {
        const int unit = i2 * 512 + t;
        const int r = unit >> 7, cu = unit & 127;   // r 0..31
        *(bf16x8*)(dst + ((size_t)b * S_LEN + q0 + r) * E_DIM + cu * 8) =
            *(const bf16x8*)(Ol + (size_t)r * 1024 + cu * 8);
    }
}

// ---------------------------------------------------------------------------
extern "C" void kernel_launch(void* const* d_in, const int* in_sizes, int n_in,
                              void* d_out, int out_size, void* d_ws, size_t ws_size,
                              hipStream_t stream)
{
    const float* x  = (const float*)d_in[0];
    const float* Wq = (const float*)d_in[1];
    const float* bq = (const float*)d_in[2];
    const float* Wk = (const float*)d_in[3];
    const float* bk = (const float*)d_in[4];
    const float* Wv = (const float*)d_in[5];
    const float* bv = (const float*)d_in[6];
    const float* Wo = (const float*)d_in[7];
    const float* bo = (const float*)d_in[8];
    float* out = (float*)d_out;

    // bf16/fp16 workspace (u16 elems), 56 MB:
    const size_t MAT = (size_t)M_ROWS * E_DIM;   // 4M elems
    const size_t WSZ = (size_t)E_DIM * E_DIM;    // 1M elems
    u16* xb   = (u16*)d_ws;          // x; later combined ctx
    u16* W3   = xb   + MAT;          // Wq|Wk|Wv concat [3072][1024]
    u16* Wob  = W3   + 3 * WSZ;
    u16* Qb   = Wob  + WSZ;
    u16* Kb   = Qb   + MAT;
    u16* Vtb  = Kb   + MAT;          // V transposed [b][e][s], FP16
    u16* ctxA = Vtb  + MAT;
    u16* ctxB = ctxA + MAT;

    // 1) convert inputs to bf16 (QKV weights in one merged launch)
    cvt_bf16<<<(int)(MAT / 1024), 256, 0, stream>>>(x, xb, (int)MAT);
    dim3 wgrid(WSZ / 1024, 3);
    cvt_w3<<<wgrid, 256, 0, stream>>>(Wq, Wk, Wv, W3);
    cvt_bf16<<<(int)(WSZ / 1024), 256, 0, stream>>>(Wo, Wob, (int)WSZ);

    // 2) fused QKV projection (Q pre-scaled, V fp16-transposed)
    dim3 qkvgrid(M_ROWS / 128, 3 * E_DIM / 128);   // 32 x 24 = 768 blocks
    gemm_qkv<<<qkvgrid, 256, 0, stream>>>(xb, W3, bq, bk, bv, Qb, Kb, Vtb);

    // 3) fused MFMA attention: 32 q/block, 64-k chunks, KSPLIT=2, XCD-pinned
    attn_v13<<<BATCH * 64 * 2, 512, 0, stream>>>(Qb, Kb, Vtb, ctxA, ctxB);

    // 4) combine k-halves into xb (x is dead)
    combine_ctx<<<(int)(MAT / 1024), 256, 0, stream>>>(ctxA, ctxB, xb, (int)MAT);

    // 5) output projection (fp32 out)
    dim3 ogrid(M_ROWS / 128, E_DIM / 128);         // 32 x 8
    gemm_wo<<<ogrid, 256, 0, stream>>>(xb, Wob, bo, out);
}